// Round 14
// baseline (53.130 us; speedup 1.0000x reference)
//
#include <hip/hip_runtime.h>
#include <math.h>

#define BATCH 512
#define HH 224
#define WW 224
#define NPIX (HH * WW)
#define NL 3
#define EPSV 1e-5f
#define GROUPS 14            // strips per image (one per WAVE), 16 rows each

// ---------------- Kernel 1: conv3x3(1->4) + relu + partial sums ----------------
// Persistent per-wave pipeline (R13 structure, verified VGPR=56 -> loads stay
// hoisted) at 2x the wave count: 7168 waves (1792 blocks) = 28 waves/CU = 7
// waves/SIMD (R13 had 3.6 -> OccupancyPercent 45, VALUBusy 39: not enough TLP).
// One wave owns a 16-row strip; 4 groups of 4 output rows; per iteration:
//   [issue next 4 row loads] sched_barrier(0) [compute from resident rv]
//   sched_barrier(0) [vmcnt wait lands at first nv use -> roll]
// Lessons kept: R2 zero clamped lanes pre-reduce; R4 direct indexing; R5 no
// min-waves clause; R6/R9 loads sink unless fenced; R12 shfl expand beats
// 3x VMEM/row; R13 per-wave partials (no LDS/barrier in conv).
__global__ __launch_bounds__(256) void conv_pool_k(
    const float* __restrict__ x, const float* __restrict__ cw,
    float* __restrict__ part)
{
  const int tid = threadIdx.x;
  const int wv = tid >> 6;
  const int lane = tid & 63;
  const int W = blockIdx.x * 4 + wv;   // global wave id
  const int b = W / GROUPS;            // image
  const int s = W % GROUPS;            // strip
  const int base = s * 16;             // first output row of strip
  const int colc = (lane < 56 ? lane : 55) * 4;  // clamped col
  const float* __restrict__ img = x + (size_t)b * NPIX;

  // 4x9 weights: uniform address -> scalar loads -> SGPRs
  float K[4][9];
#pragma unroll
  for (int o = 0; o < 4; ++o)
#pragma unroll
    for (int k = 0; k < 9; ++k) K[o][k] = cw[o * 9 + k];

  // clamped row load (address always valid; logical OOB zeroed separately)
  auto ldrow = [&](int ar) -> float4 {
    int rc = ar < 0 ? 0 : (ar > HH - 1 ? HH - 1 : ar);
    return *reinterpret_cast<const float4*>(img + (size_t)rc * WW + colc);
  };
  // expand float4 into [left, x, y, z, w, right] via cross-lane shfl
  auto expand = [&](const float4& t, float (&R)[6]) {
    float lft = __shfl_up(t.w, 1);
    R[0] = (lane == 0) ? 0.f : lft;     // image left edge
    float rgt = __shfl_down(t.x, 1);
    R[5] = (lane == 55) ? 0.f : rgt;    // image right edge (lane56 dups lane55)
    R[1] = t.x; R[2] = t.y; R[3] = t.z; R[4] = t.w;
  };

  // prologue: window rows base-1 .. base+4  (rv[k] = abs row base-1+k)
  float4 rv[6];
#pragma unroll
  for (int k = 0; k < 6; ++k) rv[k] = ldrow(base - 1 + k);
  if (s == 0) rv[0] = make_float4(0.f, 0.f, 0.f, 0.f);  // row -1

  float acc0 = 0.f, acc1 = 0.f, acc2 = 0.f, acc3 = 0.f;

#pragma unroll
  for (int j = 0; j < 4; ++j) {        // 4 groups of 4 output rows
    // ---- issue next group's loads (rows base+4j+5 .. +8) ----
    float4 nv[4];
    if (j < 3) {
#pragma unroll
      for (int k = 0; k < 4; ++k) nv[k] = ldrow(base + 4 * j + 5 + k);
    }
    __builtin_amdgcn_sched_barrier(0);  // loads may not sink into compute

    // ---- compute group j from resident rv[0..5] ----
    float E[3][6];
    expand(rv[0], E[0]);
    expand(rv[1], E[1]);
#pragma unroll
    for (int i = 0; i < 4; ++i) {      // output row base+4j+i
      expand(rv[i + 2], E[(i + 2) % 3]);
      float (&A)[6] = E[i % 3];
      float (&B)[6] = E[(i + 1) % 3];
      float (&C)[6] = E[(i + 2) % 3];
#pragma unroll
      for (int p = 0; p < 4; ++p) {
        const float a0 = A[p], a1 = A[p + 1], a2 = A[p + 2];
        const float b0 = B[p], b1 = B[p + 1], b2 = B[p + 2];
        const float c0 = C[p], c1 = C[p + 1], c2 = C[p + 2];
        float t0 = fmaf(a0, K[0][0], fmaf(a1, K[0][1], fmaf(a2, K[0][2],
                   fmaf(b0, K[0][3], fmaf(b1, K[0][4], fmaf(b2, K[0][5],
                   fmaf(c0, K[0][6], fmaf(c1, K[0][7], c2 * K[0][8]))))))));
        float t1 = fmaf(a0, K[1][0], fmaf(a1, K[1][1], fmaf(a2, K[1][2],
                   fmaf(b0, K[1][3], fmaf(b1, K[1][4], fmaf(b2, K[1][5],
                   fmaf(c0, K[1][6], fmaf(c1, K[1][7], c2 * K[1][8]))))))));
        float t2 = fmaf(a0, K[2][0], fmaf(a1, K[2][1], fmaf(a2, K[2][2],
                   fmaf(b0, K[2][3], fmaf(b1, K[2][4], fmaf(b2, K[2][5],
                   fmaf(c0, K[2][6], fmaf(c1, K[2][7], c2 * K[2][8]))))))));
        float t3 = fmaf(a0, K[3][0], fmaf(a1, K[3][1], fmaf(a2, K[3][2],
                   fmaf(b0, K[3][3], fmaf(b1, K[3][4], fmaf(b2, K[3][5],
                   fmaf(c0, K[3][6], fmaf(c1, K[3][7], c2 * K[3][8]))))))));
        acc0 += fmaxf(t0, 0.f);
        acc1 += fmaxf(t1, 0.f);
        acc2 += fmaxf(t2, 0.f);
        acc3 += fmaxf(t3, 0.f);
      }
    }
    __builtin_amdgcn_sched_barrier(0);  // compute may not sink below roll

    // ---- roll window; first nv use -> vmcnt wait lands here (after compute) ----
    if (j < 3) {
      rv[0] = rv[4]; rv[1] = rv[5];
      rv[2] = nv[0]; rv[3] = nv[1]; rv[4] = nv[2]; rv[5] = nv[3];
      // bottom strip: row 224 (loaded clamped at j==2, k==3) must be zero
      if (j == 2 && s == GROUPS - 1) rv[5] = make_float4(0.f, 0.f, 0.f, 0.f);
    }
  }

  // lanes 56..63 computed lane55's duplicate columns: zero before reduction
  if (lane >= 56) { acc0 = 0.f; acc1 = 0.f; acc2 = 0.f; acc3 = 0.f; }

  // wave-level reduce; one partial per WAVE (no LDS, no barrier)
#pragma unroll
  for (int off = 32; off > 0; off >>= 1) {
    acc0 += __shfl_down(acc0, off);
    acc1 += __shfl_down(acc1, off);
    acc2 += __shfl_down(acc2, off);
    acc3 += __shfl_down(acc3, off);
  }
  if (lane == 0) {
    *reinterpret_cast<float4*>(part + (size_t)W * 4) =
        make_float4(acc0, acc1, acc2, acc3);
  }
}

// ---------------- Kernel 2: 4-qubit circuit + BatchNorm ----------------
template <int M>
__device__ __forceinline__ void ry_g(float (&sr)[16], float (&si)[16], float th) {
  float s, c;
  sincosf(0.5f * th, &s, &c);
#pragma unroll
  for (int i = 0; i < 16; ++i) {
    if (!(i & M)) {
      const int j = i | M;
      float r0 = sr[i], q0 = si[i], r1 = sr[j], q1 = si[j];
      sr[i] = c * r0 - s * r1;  si[i] = c * q0 - s * q1;
      sr[j] = s * r0 + c * r1;  si[j] = s * q0 + c * q1;
    }
  }
}

template <int M>
__device__ __forceinline__ void rz_g(float (&sr)[16], float (&si)[16], float th) {
  float s, c;
  sincosf(0.5f * th, &s, &c);
#pragma unroll
  for (int i = 0; i < 16; ++i) {
    float a = sr[i], q = si[i];
    if (i & M) { sr[i] = a * c - q * s;  si[i] = q * c + a * s; }
    else       { sr[i] = a * c + q * s;  si[i] = q * c - a * s; }
  }
}

template <int MC, int MT>
__device__ __forceinline__ void cnot_g(float (&sr)[16], float (&si)[16]) {
#pragma unroll
  for (int i = 0; i < 16; ++i) {
    if ((i & MC) && !(i & MT)) {
      const int j = i | MT;
      float tr = sr[i]; sr[i] = sr[j]; sr[j] = tr;
      float ti = si[i]; si[i] = si[j]; si[j] = ti;
    }
  }
}

__global__ __launch_bounds__(512) void circuit_bn_k(
    const float* __restrict__ part, const float* __restrict__ params,
    const float* __restrict__ gamma, const float* __restrict__ beta,
    float* __restrict__ out)
{
  const int b = threadIdx.x;  // batch element

  // gather 14 strip partials per channel -> features
  float4 fs = make_float4(0.f, 0.f, 0.f, 0.f);
#pragma unroll
  for (int s8 = 0; s8 < GROUPS; ++s8) {
    const float4 q = *reinterpret_cast<const float4*>(&part[(b * GROUPS + s8) * 4]);
    fs.x += q.x; fs.y += q.y; fs.z += q.z; fs.w += q.w;
  }
  float f[4] = { fs.x * (1.0f / NPIX), fs.y * (1.0f / NPIX),
                 fs.z * (1.0f / NPIX), fs.w * (1.0f / NPIX) };

  float sr[16], si[16];
#pragma unroll
  for (int i = 0; i < 16; ++i) { sr[i] = 0.f; si[i] = 0.f; }
  sr[0] = 1.f;

  ry_g<8>(sr, si, f[0]);
  ry_g<4>(sr, si, f[1]);
  ry_g<2>(sr, si, f[2]);
  ry_g<1>(sr, si, f[3]);

  for (int l = 0; l < NL; ++l) {
    const float* pp = params + l * 8;
    ry_g<8>(sr, si, pp[0]); rz_g<8>(sr, si, pp[1]);
    ry_g<4>(sr, si, pp[2]); rz_g<4>(sr, si, pp[3]);
    ry_g<2>(sr, si, pp[4]); rz_g<2>(sr, si, pp[5]);
    ry_g<1>(sr, si, pp[6]); rz_g<1>(sr, si, pp[7]);
    cnot_g<8, 4>(sr, si);
    cnot_g<4, 2>(sr, si);
    cnot_g<2, 1>(sr, si);
  }

  float p[16];
#pragma unroll
  for (int i = 0; i < 16; ++i) p[i] = sr[i] * sr[i] + si[i] * si[i];

  float ev[4];
#pragma unroll
  for (int w = 0; w < 4; ++w) {
    const int m = 8 >> w;
    float ssum = 0.f;
#pragma unroll
    for (int i = 0; i < 16; ++i) ssum += (i & m) ? -p[i] : p[i];
    ev[w] = ssum;
  }

  // BatchNorm over batch of 512 (biased variance) within this single block
  float sum[4], sq[4];
#pragma unroll
  for (int w = 0; w < 4; ++w) { sum[w] = ev[w]; sq[w] = ev[w] * ev[w]; }
#pragma unroll
  for (int off = 32; off > 0; off >>= 1) {
#pragma unroll
    for (int w = 0; w < 4; ++w) {
      sum[w] += __shfl_down(sum[w], off);
      sq[w]  += __shfl_down(sq[w],  off);
    }
  }
  __shared__ float psum[8][4], psq[8][4];
  __shared__ float mean_s[4], rstd_s[4];
  const int wave = b >> 6;
  const int lane = b & 63;
  if (lane == 0) {
#pragma unroll
    for (int w = 0; w < 4; ++w) { psum[wave][w] = sum[w]; psq[wave][w] = sq[w]; }
  }
  __syncthreads();
  if (b < 4) {
    float ssum = 0.f, q = 0.f;
#pragma unroll
    for (int wv = 0; wv < 8; ++wv) { ssum += psum[wv][b]; q += psq[wv][b]; }
    const float m = ssum * (1.0f / BATCH);
    const float v = q * (1.0f / BATCH) - m * m;
    mean_s[b] = m;
    rstd_s[b] = rsqrtf(v + EPSV);
  }
  __syncthreads();
#pragma unroll
  for (int w = 0; w < 4; ++w) {
    out[b * 4 + w] = gamma[w] * (ev[w] - mean_s[w]) * rstd_s[w] + beta[w];
  }
}

extern "C" void kernel_launch(void* const* d_in, const int* in_sizes, int n_in,
                              void* d_out, int out_size, void* d_ws, size_t ws_size,
                              hipStream_t stream) {
  const float* x      = (const float*)d_in[0];
  const float* cw     = (const float*)d_in[1];
  const float* params = (const float*)d_in[2];
  const float* gamma  = (const float*)d_in[3];
  const float* beta   = (const float*)d_in[4];
  float* out  = (float*)d_out;
  float* part = (float*)d_ws;   // 7168 waves * 4 f32 partials (~114 KB)

  const int B = in_sizes[0] / NPIX;  // 512

  conv_pool_k<<<B * GROUPS / 4, 256, 0, stream>>>(x, cw, part);
  circuit_bn_k<<<1, 512, 0, stream>>>(part, params, gamma, beta, out);
}

// Round 15
// 47.436 us; speedup vs baseline: 1.1200x; 1.1200x over previous
//
#include <hip/hip_runtime.h>
#include <math.h>

#define BATCH 512
#define HH 224
#define WW 224
#define NPIX (HH * WW)
#define NL 3
#define EPSV 1e-5f
#define GROUPS 8             // strips per image (one per WAVE), 28 rows each

// ---------------- Kernel 1: conv3x3(1->4) + relu + partial sums ----------------
// R13 verbatim (best measured). Persistent per-wave pipeline, 4096 waves / 1024
// blocks; 7 groups of 4 output rows; prefetch-4 + sched_barrier fences.
__global__ __launch_bounds__(256) void conv_pool_k(
    const float* __restrict__ x, const float* __restrict__ cw,
    float* __restrict__ part)
{
  const int tid = threadIdx.x;
  const int wv = tid >> 6;
  const int lane = tid & 63;
  const int W = blockIdx.x * 4 + wv;   // global wave id
  const int b = W >> 3;                // image
  const int s = W & 7;                 // strip
  const int base = s * 28;             // first output row of strip
  const int colc = (lane < 56 ? lane : 55) * 4;  // clamped col
  const float* __restrict__ img = x + (size_t)b * NPIX;

  float K[4][9];
#pragma unroll
  for (int o = 0; o < 4; ++o)
#pragma unroll
    for (int k = 0; k < 9; ++k) K[o][k] = cw[o * 9 + k];

  auto ldrow = [&](int ar) -> float4 {
    int rc = ar < 0 ? 0 : (ar > HH - 1 ? HH - 1 : ar);
    return *reinterpret_cast<const float4*>(img + (size_t)rc * WW + colc);
  };
  auto expand = [&](const float4& t, float (&R)[6]) {
    float lft = __shfl_up(t.w, 1);
    R[0] = (lane == 0) ? 0.f : lft;     // image left edge
    float rgt = __shfl_down(t.x, 1);
    R[5] = (lane == 55) ? 0.f : rgt;    // image right edge (lane56 dups lane55)
    R[1] = t.x; R[2] = t.y; R[3] = t.z; R[4] = t.w;
  };

  float4 rv[6];
#pragma unroll
  for (int k = 0; k < 6; ++k) rv[k] = ldrow(base - 1 + k);
  if (s == 0) rv[0] = make_float4(0.f, 0.f, 0.f, 0.f);  // row -1

  float acc0 = 0.f, acc1 = 0.f, acc2 = 0.f, acc3 = 0.f;

#pragma unroll
  for (int j = 0; j < 7; ++j) {        // 7 groups of 4 output rows
    float4 nv[4];
    if (j < 6) {
#pragma unroll
      for (int k = 0; k < 4; ++k) nv[k] = ldrow(base + 4 * j + 5 + k);
    }
    __builtin_amdgcn_sched_barrier(0);  // loads may not sink into compute

    float E[3][6];
    expand(rv[0], E[0]);
    expand(rv[1], E[1]);
#pragma unroll
    for (int i = 0; i < 4; ++i) {      // output row base+4j+i
      expand(rv[i + 2], E[(i + 2) % 3]);
      float (&A)[6] = E[i % 3];
      float (&B)[6] = E[(i + 1) % 3];
      float (&C)[6] = E[(i + 2) % 3];
#pragma unroll
      for (int p = 0; p < 4; ++p) {
        const float a0 = A[p], a1 = A[p + 1], a2 = A[p + 2];
        const float b0 = B[p], b1 = B[p + 1], b2 = B[p + 2];
        const float c0 = C[p], c1 = C[p + 1], c2 = C[p + 2];
        float t0 = fmaf(a0, K[0][0], fmaf(a1, K[0][1], fmaf(a2, K[0][2],
                   fmaf(b0, K[0][3], fmaf(b1, K[0][4], fmaf(b2, K[0][5],
                   fmaf(c0, K[0][6], fmaf(c1, K[0][7], c2 * K[0][8]))))))));
        float t1 = fmaf(a0, K[1][0], fmaf(a1, K[1][1], fmaf(a2, K[1][2],
                   fmaf(b0, K[1][3], fmaf(b1, K[1][4], fmaf(b2, K[1][5],
                   fmaf(c0, K[1][6], fmaf(c1, K[1][7], c2 * K[1][8]))))))));
        float t2 = fmaf(a0, K[2][0], fmaf(a1, K[2][1], fmaf(a2, K[2][2],
                   fmaf(b0, K[2][3], fmaf(b1, K[2][4], fmaf(b2, K[2][5],
                   fmaf(c0, K[2][6], fmaf(c1, K[2][7], c2 * K[2][8]))))))));
        float t3 = fmaf(a0, K[3][0], fmaf(a1, K[3][1], fmaf(a2, K[3][2],
                   fmaf(b0, K[3][3], fmaf(b1, K[3][4], fmaf(b2, K[3][5],
                   fmaf(c0, K[3][6], fmaf(c1, K[3][7], c2 * K[3][8]))))))));
        acc0 += fmaxf(t0, 0.f);
        acc1 += fmaxf(t1, 0.f);
        acc2 += fmaxf(t2, 0.f);
        acc3 += fmaxf(t3, 0.f);
      }
    }
    __builtin_amdgcn_sched_barrier(0);  // compute may not sink below roll

    if (j < 6) {
      rv[0] = rv[4]; rv[1] = rv[5];
      rv[2] = nv[0]; rv[3] = nv[1]; rv[4] = nv[2]; rv[5] = nv[3];
      if (j == 5 && s == 7) rv[5] = make_float4(0.f, 0.f, 0.f, 0.f);  // row 224
    }
  }

  if (lane >= 56) { acc0 = 0.f; acc1 = 0.f; acc2 = 0.f; acc3 = 0.f; }

#pragma unroll
  for (int off = 32; off > 0; off >>= 1) {
    acc0 += __shfl_down(acc0, off);
    acc1 += __shfl_down(acc1, off);
    acc2 += __shfl_down(acc2, off);
    acc3 += __shfl_down(acc3, off);
  }
  if (lane == 0) {
    *reinterpret_cast<float4*>(part + (size_t)W * 4) =
        make_float4(acc0, acc1, acc2, acc3);
  }
}

// ---------------- Kernel 2a: 4-qubit circuit (1 element per lane) ----------------
// 8 blocks x 64 threads on 8 CUs (was: 1 block/1 CU, ~8-10us serial tail).
// The 24 param sin/cos are IDENTICAL across batch -> computed once by lanes
// 0..23 into LDS (kills 24 serial sincosf per thread).

__device__ __forceinline__ void ry_sc(float (&sr)[16], float (&si)[16],
                                      float s, float c, int M) {
#pragma unroll
  for (int i = 0; i < 16; ++i) {
    if (!(i & M)) {
      const int j = i | M;
      float r0 = sr[i], q0 = si[i], r1 = sr[j], q1 = si[j];
      sr[i] = c * r0 - s * r1;  si[i] = c * q0 - s * q1;
      sr[j] = s * r0 + c * r1;  si[j] = s * q0 + c * q1;
    }
  }
}

__device__ __forceinline__ void rz_sc(float (&sr)[16], float (&si)[16],
                                      float s, float c, int M) {
#pragma unroll
  for (int i = 0; i < 16; ++i) {
    float a = sr[i], q = si[i];
    if (i & M) { sr[i] = a * c - q * s;  si[i] = q * c + a * s; }
    else       { sr[i] = a * c + q * s;  si[i] = q * c - a * s; }
  }
}

__device__ __forceinline__ void cnot_g(float (&sr)[16], float (&si)[16],
                                       int MC, int MT) {
#pragma unroll
  for (int i = 0; i < 16; ++i) {
    if ((i & MC) && !(i & MT)) {
      const int j = i | MT;
      float tr = sr[i]; sr[i] = sr[j]; sr[j] = tr;
      float ti = si[i]; si[i] = si[j]; si[j] = ti;
    }
  }
}

__global__ __launch_bounds__(64) void circuit_k(
    const float* __restrict__ part, const float* __restrict__ params,
    float* __restrict__ ev_out)
{
  const int tid = threadIdx.x;
  const int e = blockIdx.x * 64 + tid;   // batch element

  __shared__ float scs[24], scc[24];     // sin/cos of 0.5*param[i]
  if (tid < 24) {
    float s, c;
    sincosf(0.5f * params[tid], &s, &c);
    scs[tid] = s; scc[tid] = c;
  }
  __syncthreads();

  // features: sum 8 strip partials per channel / NPIX
  float4 fs = make_float4(0.f, 0.f, 0.f, 0.f);
#pragma unroll
  for (int s8 = 0; s8 < GROUPS; ++s8) {
    const float4 q = *reinterpret_cast<const float4*>(&part[(e * GROUPS + s8) * 4]);
    fs.x += q.x; fs.y += q.y; fs.z += q.z; fs.w += q.w;
  }
  const float f[4] = { fs.x * (1.0f / NPIX), fs.y * (1.0f / NPIX),
                       fs.z * (1.0f / NPIX), fs.w * (1.0f / NPIX) };

  float sr[16], si[16];
#pragma unroll
  for (int i = 0; i < 16; ++i) { sr[i] = 0.f; si[i] = 0.f; }
  sr[0] = 1.f;

  // feature RY gates (per-element sincos, only 4 of them)
#pragma unroll
  for (int w = 0; w < 4; ++w) {
    float s, c;
    sincosf(0.5f * f[w], &s, &c);
    ry_sc(sr, si, s, c, 8 >> w);
  }

#pragma unroll
  for (int l = 0; l < NL; ++l) {
#pragma unroll
    for (int w = 0; w < 4; ++w) {
      const int idx = l * 8 + w * 2;
      ry_sc(sr, si, scs[idx],     scc[idx],     8 >> w);
      rz_sc(sr, si, scs[idx + 1], scc[idx + 1], 8 >> w);
    }
    cnot_g(sr, si, 8, 4);
    cnot_g(sr, si, 4, 2);
    cnot_g(sr, si, 2, 1);
  }

  float p[16];
#pragma unroll
  for (int i = 0; i < 16; ++i) p[i] = sr[i] * sr[i] + si[i] * si[i];

#pragma unroll
  for (int w = 0; w < 4; ++w) {
    const int m = 8 >> w;
    float ssum = 0.f;
#pragma unroll
    for (int i = 0; i < 16; ++i) ssum += (i & m) ? -p[i] : p[i];
    ev_out[e * 4 + w] = ssum;
  }
}

// ---------------- Kernel 2b: BatchNorm over batch (deterministic) ----------------
__global__ __launch_bounds__(512) void bn_k(
    const float* __restrict__ ev_in, const float* __restrict__ gamma,
    const float* __restrict__ beta, float* __restrict__ out)
{
  const int b = threadIdx.x;   // batch element
  const float4 e4 = *reinterpret_cast<const float4*>(&ev_in[b * 4]);
  float ev[4] = { e4.x, e4.y, e4.z, e4.w };

  float sum[4], sq[4];
#pragma unroll
  for (int w = 0; w < 4; ++w) { sum[w] = ev[w]; sq[w] = ev[w] * ev[w]; }
#pragma unroll
  for (int off = 32; off > 0; off >>= 1) {
#pragma unroll
    for (int w = 0; w < 4; ++w) {
      sum[w] += __shfl_down(sum[w], off);
      sq[w]  += __shfl_down(sq[w],  off);
    }
  }
  __shared__ float psum[8][4], psq[8][4];
  __shared__ float mean_s[4], rstd_s[4];
  const int wave = b >> 6;
  const int lane = b & 63;
  if (lane == 0) {
#pragma unroll
    for (int w = 0; w < 4; ++w) { psum[wave][w] = sum[w]; psq[wave][w] = sq[w]; }
  }
  __syncthreads();
  if (b < 4) {
    float ssum = 0.f, q = 0.f;
#pragma unroll
    for (int wv = 0; wv < 8; ++wv) { ssum += psum[wv][b]; q += psq[wv][b]; }
    const float m = ssum * (1.0f / BATCH);
    const float v = q * (1.0f / BATCH) - m * m;
    mean_s[b] = m;
    rstd_s[b] = rsqrtf(v + EPSV);
  }
  __syncthreads();
#pragma unroll
  for (int w = 0; w < 4; ++w) {
    out[b * 4 + w] = gamma[w] * (ev[w] - mean_s[w]) * rstd_s[w] + beta[w];
  }
}

extern "C" void kernel_launch(void* const* d_in, const int* in_sizes, int n_in,
                              void* d_out, int out_size, void* d_ws, size_t ws_size,
                              hipStream_t stream) {
  const float* x      = (const float*)d_in[0];
  const float* cw     = (const float*)d_in[1];
  const float* params = (const float*)d_in[2];
  const float* gamma  = (const float*)d_in[3];
  const float* beta   = (const float*)d_in[4];
  float* out  = (float*)d_out;
  float* part = (float*)d_ws;                       // 4096 waves * 4 f32 (64 KB)
  float* ev   = (float*)d_ws + BATCH * GROUPS * 4;  // 512 * 4 f32 (8 KB)

  const int B = in_sizes[0] / NPIX;  // 512

  conv_pool_k<<<B * GROUPS / 4, 256, 0, stream>>>(x, cw, part);
  circuit_k<<<BATCH / 64, 64, 0, stream>>>(part, params, ev);
  bn_k<<<1, 512, 0, stream>>>(ev, gamma, beta, out);
}